// Round 6
// baseline (77.208 us; speedup 1.0000x reference)
//
#include <hip/hip_runtime.h>
#include <math.h>

// Problem constants (fixed by reference setup_inputs)
#define BB 128
#define LL 512
#define DD 256
#define TT 64
#define GG 8       // LL / TT
#define NQ (DD/4)  // 64 f32x4 per D-row

typedef float f32x4 __attribute__((ext_vector_type(4)));

__device__ __forceinline__ float sigm(float x) {
    return 1.0f / (1.0f + __expf(-x));
}
__device__ __forceinline__ f32x4 sigm4(f32x4 z) {
    f32x4 r;
    r.x = sigm(z.x); r.y = sigm(z.y); r.z = sigm(z.z); r.w = sigm(z.w);
    return r;
}

// ---------------- K1: summaries only ----------------
// grid = 1024 blocks (b, t8-chunk) x 256 threads. Wave w owns t-groups
// (t8*8 + 2w, +1), i.e. 16 rows. Emits rowMean[b,t] (hw mean over D) and
// colpart[bk,d] (hw summed over this block's 8 t-groups). No bulk writes.
__global__ __launch_bounds__(256) void k_sum(
    const f32x4* __restrict__ aco4, const f32x4* __restrict__ vis4,
    float* __restrict__ rowMean,   // [BB*TT]
    float* __restrict__ colpart)   // [1024*DD]
{
    const int tid  = threadIdx.x;
    const int w    = tid >> 6;
    const int lane = tid & 63;
    const int bk   = blockIdx.x;
    const int b    = bk >> 3;
    const int t8   = bk & 7;

    const size_t rowBase = (size_t)b * LL + (size_t)t8 * 64 + (size_t)w * 16;

    // hw = 0.5*(mean_a + mean_v) = (sum over 8 rows of (a+v)) / 16
    f32x4 hw0 = 0.f, hw1 = 0.f;
#pragma unroll
    for (int j = 0; j < 8; ++j)
        hw0 += aco4[(rowBase + j) * NQ + lane] + vis4[(rowBase + j) * NQ + lane];
#pragma unroll
    for (int j = 0; j < 8; ++j)
        hw1 += aco4[(rowBase + 8 + j) * NQ + lane] + vis4[(rowBase + 8 + j) * NQ + lane];
    hw0 *= 0.0625f;
    hw1 *= 0.0625f;

    // row means over D for the wave's two t-groups (64 lanes = 1 wave)
    float s0 = hw0.x + hw0.y + hw0.z + hw0.w;
    float s1 = hw1.x + hw1.y + hw1.z + hw1.w;
#pragma unroll
    for (int off = 32; off > 0; off >>= 1) {
        s0 += __shfl_xor(s0, off, 64);
        s1 += __shfl_xor(s1, off, 64);
    }
    if (lane == 0) {
        const int btBase = b * TT + t8 * 8 + 2 * w;
        rowMean[btBase]     = s0 * (1.0f / DD);
        rowMean[btBase + 1] = s1 * (1.0f / DD);
    }

    // per-block column partial (sum of hw over 8 t-groups, per d)
    __shared__ __align__(16) float red[4][DD];
    *reinterpret_cast<f32x4*>(&red[w][lane * 4]) = hw0 + hw1;
    __syncthreads();
    colpart[(size_t)bk * DD + tid] =
        red[0][tid] + red[1][tid] + red[2][tid] + red[3][tid];
}

// ---------------- K2: gates ----------------
// grid = BB x 256 threads. h_att = sigm(rowMean @ Wh^T + bh),
// w_att = sigm(colMean @ Ww^T + bw).
__global__ __launch_bounds__(256) void k_gates(
    const float* __restrict__ colpart, const float* __restrict__ rowMean,
    const float* __restrict__ Wh, const float* __restrict__ bh,
    const float* __restrict__ Ww, const float* __restrict__ bw,
    float* __restrict__ h_att, float* __restrict__ w_att)
{
    const int b = blockIdx.x;
    const int d = threadIdx.x;

    __shared__ float rm[TT];
    __shared__ float cm[DD];

    {
        float cs = 0.f;
#pragma unroll
        for (int p = 0; p < 8; ++p)
            cs += colpart[(size_t)(b * 8 + p) * DD + d];
        cm[d] = cs * (1.0f / TT);
        if (d < TT) rm[d] = rowMean[b * TT + d];
    }
    __syncthreads();

    if (d < TT) {
        float acc = bh[d];
#pragma unroll 8
        for (int j = 0; j < TT; ++j) acc += rm[j] * Wh[d * TT + j];
        h_att[b * TT + d] = sigm(acc);
    }
    {
        float acc = bw[d];
        const f32x4* Wr = reinterpret_cast<const f32x4*>(Ww + (size_t)d * DD);
#pragma unroll 8
        for (int kq = 0; kq < NQ; ++kq) {
            f32x4 wq = Wr[kq];
            acc += cm[4 * kq] * wq.x + cm[4 * kq + 1] * wq.y +
                   cm[4 * kq + 2] * wq.z + cm[4 * kq + 3] * wq.w;
        }
        w_att[b * DD + d] = sigm(acc);
    }
}

// ---------------- K3: pool-recompute + apply (register-only, no LDS) ----------------
// grid = 2048 blocks x 256 threads. Block covers 4 t-groups; each 64-lane
// wave owns one (b,t) group. Thread owns the full 8-row column (one f32x4
// slot q) -> pools in registers, recomputes c_att, applies, NT-stores.
__global__ __launch_bounds__(256) void k_apply(
    const f32x4* __restrict__ aco4, const f32x4* __restrict__ vis4,
    const int* __restrict__ isb,
    const float* __restrict__ h_att, const float* __restrict__ w_att,
    const float* __restrict__ cw, const float* __restrict__ cb,
    f32x4* __restrict__ out4)
{
    const int tid = threadIdx.x;
    const int sub = tid >> 6;          // which t within this block's chunk
    const int q   = tid & 63;          // f32x4 column
    const int bk  = blockIdx.x;
    const int b   = bk >> 4;           // 16 chunks per batch
    const int t   = (bk & 15) * 4 + sub;

    const size_t rowBase = (size_t)b * LL + (size_t)t * GG;
    const size_t N4      = (size_t)BB * LL * NQ;

    f32x4 A[8], V[8];
#pragma unroll
    for (int j = 0; j < 8; ++j) A[j] = aco4[(rowBase + j) * NQ + q];
#pragma unroll
    for (int j = 0; j < 8; ++j) V[j] = vis4[(rowBase + j) * NQ + q];

    f32x4 pa = A[0] + A[1] + A[2] + A[3] + A[4] + A[5] + A[6] + A[7];
    f32x4 pv = V[0] + V[1] + V[2] + V[3] + V[4] + V[5] + V[6] + V[7];
    pa *= 0.125f;
    pv *= 0.125f;

    const f32x4 c  = sigm4(cw[0] * pa + cw[1] * pv + cb[0]);
    const float h  = h_att[b * TT + t];                                   // wave-uniform
    const f32x4 w4 = *reinterpret_cast<const f32x4*>(w_att + (size_t)b * DD + q * 4);
    const f32x4 sc = (h + w4 + c) * (1.0f / 3.0f);

#pragma unroll
    for (int j = 0; j < 8; ++j) {
        const size_t ridx = rowBase + j;
        const size_t idx  = ridx * NQ + q;
        const int m = isb[ridx];                                          // wave-uniform scalar
        f32x4 a = A[j];
        f32x4 v = V[j];
        if (m == 1) { a *= sc; v *= sc; }
        __builtin_nontemporal_store(a, &out4[idx]);
        __builtin_nontemporal_store(v, &out4[N4 + idx]);
    }
}

extern "C" void kernel_launch(void* const* d_in, const int* in_sizes, int n_in,
                              void* d_out, int out_size, void* d_ws, size_t ws_size,
                              hipStream_t stream) {
    const f32x4* aco = (const f32x4*)d_in[0];
    const f32x4* vis = (const f32x4*)d_in[1];
    const int*   isb = (const int*)d_in[2];
    const float* Wh  = (const float*)d_in[3];
    const float* bh  = (const float*)d_in[4];
    const float* Ww  = (const float*)d_in[5];
    const float* bw  = (const float*)d_in[6];
    const float* cw  = (const float*)d_in[7];
    const float* cb  = (const float*)d_in[8];
    f32x4* out = (f32x4*)d_out;

    float* ws = (float*)d_ws;
    float* rowMean = ws;                          // BB*TT      = 8192 floats
    float* colpart = rowMean + BB * TT;           // 1024*DD    = 262144 floats
    float* h_att   = colpart + 1024 * DD;         // BB*TT      = 8192 floats
    float* w_att   = h_att + BB * TT;             // BB*DD      = 32768 floats

    k_sum<<<1024, 256, 0, stream>>>(aco, vis, rowMean, colpart);
    k_gates<<<BB, 256, 0, stream>>>(colpart, rowMean, Wh, bh, Ww, bw, h_att, w_att);
    k_apply<<<2048, 256, 0, stream>>>(aco, vis, isb, h_att, w_att, cw, cb, out);
}